// Round 6
// baseline (127.438 us; speedup 1.0000x reference)
//
#include <hip/hip_runtime.h>
#include <hip/hip_fp16.h>

// 3-layer GCN on MI355X — R22: barrier-free MFMA phase B (W2 from L2, no LDS).
// R21 lesson: agg2 16-deep window = neutral -> agg2 is at its random-gather
// floor; aggregation tier is done. R22 targets gemm12's schedule: post-MFMA
// (R20) the K-loop's 18KB W2 LDS staging + 8 barriers + prefetch regs are
// structural overhead for ~80 cycles of MFMA. W2t fp16 is 64KB, L2/L1-hot,
// shared by all 1250 blocks; B-fragments are 16B coalesced reads (each 64B
// line consumed by 4 lanes). So phase B reads B straight from global:
// 8 k-steps x {1 LDS A-read, 2 global B-reads, 2 MFMA}, ZERO barriers.
// LDS 33->15.3KB (8 blocks/CU wave-cap, was 4), VGPR drops (no pf regs).
// NOTE R7/R13 ("W2 must be LDS-staged") was measured on the fp32-VALU kernel
// reading W2 per-element; intensity is now 60x lower -> re-test justified.
// Structure: k_prep (W2 transpose fp16 + cursor zero) -> k_fill ->
//   k_gemm12 (agg1 + L1 + MFMA L2 -> t2h fp16) -> k_agg2 -> k_agg3.
// Fragment layouts (m89/m97-verified): A/B: row(m)|col(n) = lane&15,
// k = (lane>>4)*8 + i (b128 per lane); C/D: col = lane&15,
// row = (lane>>4)*4 + reg.
// Lessons (all measured): R3 multi-float atomic scatter=186us; R4 cooperative
// grid.sync~100us each; R9/R11/R16 MB=32 loses 2-6us; R14 128t blocks can't
// hide chunk barriers; R17 8-node k-split phase B = VGPR 128, occ 17%, -11us
// (phase B must stay low-VGPR); R18 coop stage-0 = +0.8us; R19 fp16 t2s +
// 16-lane agg3 = -9.9us, absmax 1.2e-4 OK; R20 MFMA fp16 phase B = -13.3us,
// absmax unchanged (storage-dominated); R21 16-deep agg2 = neutral.

constexpr int NN  = 20000;  // nodes
constexpr int NE  = 320000; // edges
constexpr int F0  = 10;     // input feats
constexpr int F1  = 256;    // layer1 out
constexpr int F2  = 128;    // layer2 out
constexpr int MB  = 16;     // nodes per gemm12 tile (= MFMA M)
constexpr int CAP = 64;     // bucket capacity (max in-deg ~36)
constexpr int EMAX = 48;    // staged edges per node

typedef _Float16 f16x8 __attribute__((ext_vector_type(8)));
typedef float    f32x4 __attribute__((ext_vector_type(4)));

constexpr int H1S = 264;    // h1h row stride (f16): mult of 8, 528B rows

// ---------- adjacency fill ----------

__global__ void k_fill(const int* __restrict__ src, const int* __restrict__ dst,
                       int* cursor, int* __restrict__ col) {
  int e = blockIdx.x * 256 + threadIdx.x;
  if (e >= NE) return;
  const int d = dst[e], s = src[e];
  const int pos = atomicAdd(&cursor[d], 1) & (CAP - 1);
  col[d * CAP + pos] = s;
}

// ---------- prep: W2 transpose to fp16 [n][k] + cursor zeroing ----------

__global__ __launch_bounds__(256) void k_prep(const float* __restrict__ W2,
                                              _Float16* __restrict__ W2t,
                                              int* __restrict__ cursor) {
  const int t = blockIdx.x * 256 + threadIdx.x;  // 32768 total
  const int n = t >> 8;        // 0..127
  const int k = t & 255;       // 0..255
  W2t[n * 256 + k] = (_Float16)W2[k * F2 + n];
  if (t < NN) cursor[t] = 0;
}

// ---------- fused: agg1 -> h1 = relu(.) fp16 -> t2h = fp16(dinv*(h1 W2)) ----

__global__ __launch_bounds__(256) void k_gemm12(
    const float* __restrict__ x, const int* __restrict__ cursor,
    const int* __restrict__ col, const float* __restrict__ W1,
    const float* __restrict__ b1, const _Float16* __restrict__ W2t,
    _Float16* __restrict__ t2h) {
  __shared__ float alds[MB * F0];                       // 640 B
  __shared__ float din[MB];                             // 64 B
  __shared__ __align__(16) _Float16 h1h[MB * H1S];      // 8.25 KB
  __shared__ int   es[MB][EMAX];                        // 3 KB
  __shared__ float ew[MB][EMAX];                        // 3 KB
  const int tid = threadIdx.x;
  const int n0 = blockIdx.x * MB;
  // stage 0a: cooperative edge staging — 16 threads per node, one edge each.
  {
    const int m = tid >> 4;
    const int j0 = tid & 15;
    const int n = n0 + m;
    const int degraw = cursor[n];
    const int deg = min(degraw, EMAX);
    const int base = n * CAP;
    if (j0 == 0) din[m] = rsqrtf((float)(degraw + 1));
    for (int j = j0; j < deg; j += 16) {
      const int s = col[base + j];
      es[m][j] = s;
      ew[m][j] = rsqrtf((float)(cursor[s] + 1));
    }
  }
  __syncthreads();
  // stage 0b: x-gathers with LDS-sourced addresses (independent, pipelined)
  {
    const int m = tid >> 4;
    const int f = tid & 15;
    if (f < F0) {
      const int n = n0 + m;
      const int deg = min(cursor[n], EMAX);
      const float di = din[m];
      float acc = x[n * F0 + f] * di;  // self-loop
      int j = 0;
      for (; j + 3 < deg; j += 4) {
        const int s0 = es[m][j],     s1 = es[m][j + 1];
        const int s2 = es[m][j + 2], s3 = es[m][j + 3];
        const float q0 = ew[m][j],     q1 = ew[m][j + 1];
        const float q2 = ew[m][j + 2], q3 = ew[m][j + 3];
        acc += x[s0 * F0 + f] * q0 + x[s1 * F0 + f] * q1 +
               x[s2 * F0 + f] * q2 + x[s3 * F0 + f] * q3;
      }
      for (; j < deg; ++j) acc += x[es[m][j] * F0 + f] * ew[m][j];
      alds[m * F0 + f] = di * acc;
    }
  }
  __syncthreads();
  {  // phase A: thread = layer-1 channel c; writes h1h fp16 (k-contig per m)
    const int c = tid;
    float w1r[F0];
#pragma unroll
    for (int k = 0; k < F0; ++k) w1r[k] = W1[k * F1 + c];
    const float bb = b1[c];
#pragma unroll
    for (int m = 0; m < MB; ++m) {
      float acc = bb;
#pragma unroll
      for (int k = 0; k < F0; ++k) acc += alds[m * F0 + k] * w1r[k];
      h1h[m * H1S + c] = (_Float16)fmaxf(acc, 0.f);
    }
  }
  __syncthreads();
  // phase B: barrier-free MFMA. Wave wv owns 2 output tiles (16x16) at
  // n-offsets wv*32, wv*32+16. B-fragments straight from L2-resident W2t:
  // lanes (lg,lr) read (nt0+lr)*512 + kb*2 + lg*16 bytes -> each 64B line
  // fully consumed by 4 lanes, 16 lines/instr, shared across all blocks.
  const int lane = tid & 63;
  const int wv   = tid >> 6;
  const int lr   = lane & 15;
  const int lg   = lane >> 4;
  const int nt0  = wv * 32;
  f32x4 acc0 = {0.f, 0.f, 0.f, 0.f};
  f32x4 acc1 = {0.f, 0.f, 0.f, 0.f};
  const f16x8* brow0 = (const f16x8*)&W2t[(nt0 + lr) * 256 + lg * 8];
  const f16x8* brow1 = (const f16x8*)&W2t[(nt0 + 16 + lr) * 256 + lg * 8];
  const _Float16* arow = &h1h[lr * H1S + lg * 8];
#pragma unroll
  for (int ks = 0; ks < 8; ++ks) {  // K=256 in 8 steps of 32
    const f16x8 av  = *(const f16x8*)(arow + ks * 32);
    const f16x8 b0  = brow0[ks * 4];   // f16x8 index: 32 f16 = 4 per step
    const f16x8 b1v = brow1[ks * 4];
    acc0 = __builtin_amdgcn_mfma_f32_16x16x32_f16(av, b0, acc0, 0, 0, 0);
    acc1 = __builtin_amdgcn_mfma_f32_16x16x32_f16(av, b1v, acc1, 0, 0, 0);
  }
  // epilogue: C/D layout col=lane&15, row=(lane>>4)*4+reg; scale by din[row]
#pragma unroll
  for (int r = 0; r < 4; ++r) {
    const int row = lg * 4 + r;
    const float dn = din[row];
    t2h[(size_t)(n0 + row) * F2 + nt0 + lr]      = (_Float16)(acc0[r] * dn);
    t2h[(size_t)(n0 + row) * F2 + nt0 + 16 + lr] = (_Float16)(acc1[r] * dn);
  }
}

// ---------- layer-2 aggregation + layer-3 transform ----------
// 2 nodes per wave: half-wave (32 lanes) per node, 8 B/lane (4 fp16);
// 16 gathers in flight (deg~16).

__device__ inline void acc_h4(uint2 u, float& a0, float& a1, float& a2, float& a3) {
  union { uint2 u; __half2 h[2]; } pk;
  pk.u = u;
  const float2 f0 = __half22float2(pk.h[0]);
  const float2 f1 = __half22float2(pk.h[1]);
  a0 += f0.x; a1 += f0.y; a2 += f1.x; a3 += f1.y;
}

__global__ __launch_bounds__(256) void k_agg2(
    const __half* __restrict__ t2h, const int* __restrict__ cursor,
    const int* __restrict__ col, const float* __restrict__ b2,
    const float* __restrict__ W3, float* __restrict__ t3s) {
  const int wave = (blockIdx.x * 256 + threadIdx.x) >> 6;
  const int lane = threadIdx.x & 63;
  const int half = lane >> 5;        // 0 or 1
  const int li   = lane & 31;
  const int n    = wave * 2 + half;  // 2500 blocks cover 20000 exactly
  if (n >= NN) return;
  const int deg = cursor[n];
  const int base = n * CAP;
  const int fx = li * 4;
  float a0 = 0.f, a1 = 0.f, a2 = 0.f, a3 = 0.f;
  acc_h4(*(const uint2*)&t2h[(size_t)n * F2 + fx], a0, a1, a2, a3);  // self
  int k = 0;
  for (; k + 15 < deg; k += 16) {  // 16 coalesced 256B gathers in flight
    int ss[16];
#pragma unroll
    for (int j = 0; j < 16; ++j) ss[j] = col[base + k + j];
    uint2 vv[16];
#pragma unroll
    for (int j = 0; j < 16; ++j)
      vv[j] = *(const uint2*)&t2h[(size_t)ss[j] * F2 + fx];
#pragma unroll
    for (int j = 0; j < 16; ++j) acc_h4(vv[j], a0, a1, a2, a3);
  }
  for (; k + 7 < deg; k += 8) {
    int ss[8];
#pragma unroll
    for (int j = 0; j < 8; ++j) ss[j] = col[base + k + j];
    uint2 vv[8];
#pragma unroll
    for (int j = 0; j < 8; ++j)
      vv[j] = *(const uint2*)&t2h[(size_t)ss[j] * F2 + fx];
#pragma unroll
    for (int j = 0; j < 8; ++j) acc_h4(vv[j], a0, a1, a2, a3);
  }
  for (; k + 3 < deg; k += 4) {
    int ss[4];
#pragma unroll
    for (int j = 0; j < 4; ++j) ss[j] = col[base + k + j];
    uint2 vv[4];
#pragma unroll
    for (int j = 0; j < 4; ++j)
      vv[j] = *(const uint2*)&t2h[(size_t)ss[j] * F2 + fx];
#pragma unroll
    for (int j = 0; j < 4; ++j) acc_h4(vv[j], a0, a1, a2, a3);
  }
  for (; k < deg; ++k) {
    acc_h4(*(const uint2*)&t2h[(size_t)col[base + k] * F2 + fx], a0, a1, a2, a3);
  }
  const float di = rsqrtf((float)(deg + 1));
  const float4 bb = *(const float4*)&b2[fx];
  const float4 w3 = *(const float4*)&W3[fx];
  const float h0 = fmaxf(di * a0 + bb.x, 0.f);
  const float h1 = fmaxf(di * a1 + bb.y, 0.f);
  const float h2 = fmaxf(di * a2 + bb.z, 0.f);
  const float h3 = fmaxf(di * a3 + bb.w, 0.f);
  float p = (h0 * w3.x + h1 * w3.y) + (h2 * w3.z + h3 * w3.w);
#pragma unroll
  for (int off = 16; off > 0; off >>= 1) p += __shfl_down(p, off);  // within half
  if (li == 0) t3s[n] = di * p;
}

// ---------- layer-3 aggregation ----------
// 4 nodes per wave, 16 lanes per node -> coalesced col reads, 16-wide gathers.

__global__ __launch_bounds__(256) void k_agg3(
    const float* __restrict__ t3s, const int* __restrict__ cursor,
    const int* __restrict__ col, const float* __restrict__ b3,
    float* __restrict__ out) {
  const int wave = (blockIdx.x * 256 + threadIdx.x) >> 6;
  const int lane = threadIdx.x & 63;
  const int sub  = lane >> 4;       // 0..3
  const int li   = lane & 15;
  const int n    = wave * 4 + sub;  // 1250 blocks x 16 nodes cover 20000 exactly
  if (n >= NN) return;
  const int deg = cursor[n];
  const int base = n * CAP;
  float acc = 0.f;
  for (int j = li; j < deg; j += 16) acc += t3s[col[base + j]];
  acc += __shfl_xor(acc, 8);
  acc += __shfl_xor(acc, 4);
  acc += __shfl_xor(acc, 2);
  acc += __shfl_xor(acc, 1);
  if (li == 0)
    out[n] = rsqrtf((float)(deg + 1)) * (acc + t3s[n]) + b3[0];
}

extern "C" void kernel_launch(void* const* d_in, const int* in_sizes, int n_in,
                              void* d_out, int out_size, void* d_ws, size_t ws_size,
                              hipStream_t stream) {
  const float* x = (const float*)d_in[0];
  const int* ei = (const int*)d_in[1];
  const int* srcv = ei;       // edge_index[0]
  const int* dstv = ei + NE;  // edge_index[1]
  const float* W1 = (const float*)d_in[2];
  const float* b1 = (const float*)d_in[3];
  const float* W2 = (const float*)d_in[4];
  const float* b2 = (const float*)d_in[5];
  const float* W3 = (const float*)d_in[6];
  const float* b3 = (const float*)d_in[7];
  float* out = (float*)d_out;

  char* w = (char*)d_ws;
  auto alloc = [&](size_t bytes) -> void* {
    void* p = (void*)w;
    w += (bytes + 255) & ~(size_t)255;
    return p;
  };
  int*      cursor = (int*)     alloc(NN * 4);
  int*      col    = (int*)     alloc((size_t)NN * CAP * 4);
  _Float16* t2h    = (_Float16*)alloc((size_t)NN * F2 * 2);
  float*    t3s    = (float*)   alloc(NN * 4);
  _Float16* W2t    = (_Float16*)alloc((size_t)F2 * F1 * 2);

  k_prep<<<(F1 * F2) / 256, 256, 0, stream>>>(W2, W2t, cursor);
  k_fill<<<(NE + 255) / 256, 256, 0, stream>>>(srcv, dstv, cursor, col);
  k_gemm12<<<NN / MB, 256, 0, stream>>>(x, cursor, col, W1, b1, W2t, t2h);
  k_agg2<<<NN / 8, 256, 0, stream>>>((const __half*)t2h, cursor, col, b2, W3, t3s);
  k_agg3<<<(NN + 15) / 16, 256, 0, stream>>>(t3s, cursor, col, b3, out);
}

// Round 7
// 125.051 us; speedup vs baseline: 1.0191x; 1.0191x over previous
//
#include <hip/hip_runtime.h>
#include <hip/hip_fp16.h>

// 3-layer GCN on MI355X — R23: best-known composite (R20 phase B restored)
// + int2-vectorized k_fill.
// R22 lesson (measured): W2 from L2 in phase B = +2-3us vs LDS-chunked staging
// even at MFMA intensity (16 global B-loads/wave expose L2 latency; 4 blk/CU
// TLP insufficient) -> R20's chunked reg-prefetch staging is the optimum.
// R23: revert phase B to R20-exact; keep R21 prep fusion + 16-deep agg2
// (neutral); NEW: k_fill processes 2 edges/thread via int2 loads (halves
// index-load instructions; atomic/write volume unchanged).
// Structure: k_prep (W2 transpose fp16 + cursor zero) -> k_fill ->
//   k_gemm12 (agg1 + L1 + MFMA L2 -> t2h fp16) -> k_agg2 -> k_agg3.
// Fragment layouts (m89/m97-verified): A/B: row(m)|col(n) = lane&15,
// k = (lane>>4)*8 + i (b128 per lane); C/D: col = lane&15,
// row = (lane>>4)*4 + reg.
// Lessons (all measured): R3 multi-float atomic scatter=186us; R4 cooperative
// grid.sync~100us each; R7/R13/R22 W2 from global in phase B = latency-bound
// at ANY intensity — W2 must be LDS-staged; R9/R11/R16 MB=32 loses 2-6us;
// R14 128t blocks can't hide chunk barriers; R17 8-node k-split phase B =
// VGPR 128, occ 17%, -11us (phase B must stay low-VGPR); R18 coop stage-0 =
// +0.8us; R19 fp16 t2s + 16-lane agg3 = -9.9us, absmax 1.2e-4 OK; R20 MFMA
// fp16 phase B = -13.3us; R21 16-deep agg2 + prep fusion = neutral;
// R22 barrier-free global-B phase B = +2-3us REGRESSION.

constexpr int NN  = 20000;  // nodes
constexpr int NE  = 320000; // edges
constexpr int F0  = 10;     // input feats
constexpr int F1  = 256;    // layer1 out
constexpr int F2  = 128;    // layer2 out
constexpr int MB  = 16;     // nodes per gemm12 tile (= MFMA M)
constexpr int CAP = 64;     // bucket capacity (max in-deg ~36)
constexpr int EMAX = 48;    // staged edges per node

typedef _Float16 f16x8 __attribute__((ext_vector_type(8)));
typedef float    f32x4 __attribute__((ext_vector_type(4)));

constexpr int H1S = 264;    // h1h row stride (f16): mult of 8, 528B rows
constexpr int BKC = 64;     // K per staged chunk
constexpr int W2S = 72;     // w2t_lds row stride (f16): mult of 8, 144B rows

// ---------- adjacency fill: 2 edges/thread via int2 ----------

__global__ void k_fill(const int* __restrict__ src, const int* __restrict__ dst,
                       int* cursor, int* __restrict__ col) {
  const int t = blockIdx.x * 256 + threadIdx.x;  // 160000 threads
  if (t * 2 >= NE) return;
  const int2 s2 = *(const int2*)&src[t * 2];
  const int2 d2 = *(const int2*)&dst[t * 2];
  const int p0 = atomicAdd(&cursor[d2.x], 1) & (CAP - 1);
  col[d2.x * CAP + p0] = s2.x;
  const int p1 = atomicAdd(&cursor[d2.y], 1) & (CAP - 1);
  col[d2.y * CAP + p1] = s2.y;
}

// ---------- prep: W2 transpose to fp16 [n][k] + cursor zeroing ----------

__global__ __launch_bounds__(256) void k_prep(const float* __restrict__ W2,
                                              _Float16* __restrict__ W2t,
                                              int* __restrict__ cursor) {
  const int t = blockIdx.x * 256 + threadIdx.x;  // 32768 total
  const int n = t >> 8;        // 0..127
  const int k = t & 255;       // 0..255
  W2t[n * 256 + k] = (_Float16)W2[k * F2 + n];
  if (t < NN) cursor[t] = 0;
}

// ---------- fused: agg1 -> h1 = relu(.) fp16 -> t2h = fp16(dinv*(h1 W2)) ----

__global__ __launch_bounds__(256) void k_gemm12(
    const float* __restrict__ x, const int* __restrict__ cursor,
    const int* __restrict__ col, const float* __restrict__ W1,
    const float* __restrict__ b1, const _Float16* __restrict__ W2t,
    _Float16* __restrict__ t2h) {
  __shared__ float alds[MB * F0];                       // 640 B
  __shared__ float din[MB];                             // 64 B
  __shared__ __align__(16) _Float16 h1h[MB * H1S];      // 8.25 KB
  __shared__ __align__(16) _Float16 w2t[F2 * W2S];      // 18 KB
  __shared__ int   es[MB][EMAX];                        // 3 KB
  __shared__ float ew[MB][EMAX];                        // 3 KB
  const int tid = threadIdx.x;
  const int n0 = blockIdx.x * MB;
  // W2t chunk-0 prefetch FIRST: in flight under all of stage 0.
  // uint4 index map: u in {tid, tid+256, tid+512, tid+768}:
  //   n = u>>3, koff16B = u&7 ; global uint4 idx = n*32 + kc*8 + (u&7)
  const uint4* W2t4 = (const uint4*)W2t;
  const int gb = ((tid >> 3) << 5) + (tid & 7);
  uint4 pf0 = W2t4[gb];
  uint4 pf1 = W2t4[gb + 1024];
  uint4 pf2 = W2t4[gb + 2048];
  uint4 pf3 = W2t4[gb + 3072];
  // stage 0a: cooperative edge staging — 16 threads per node, one edge each.
  {
    const int m = tid >> 4;
    const int j0 = tid & 15;
    const int n = n0 + m;
    const int degraw = cursor[n];
    const int deg = min(degraw, EMAX);
    const int base = n * CAP;
    if (j0 == 0) din[m] = rsqrtf((float)(degraw + 1));
    for (int j = j0; j < deg; j += 16) {
      const int s = col[base + j];
      es[m][j] = s;
      ew[m][j] = rsqrtf((float)(cursor[s] + 1));
    }
  }
  __syncthreads();
  // stage 0b: x-gathers with LDS-sourced addresses (independent, pipelined)
  {
    const int m = tid >> 4;
    const int f = tid & 15;
    if (f < F0) {
      const int n = n0 + m;
      const int deg = min(cursor[n], EMAX);
      const float di = din[m];
      float acc = x[n * F0 + f] * di;  // self-loop
      int j = 0;
      for (; j + 3 < deg; j += 4) {
        const int s0 = es[m][j],     s1 = es[m][j + 1];
        const int s2 = es[m][j + 2], s3 = es[m][j + 3];
        const float q0 = ew[m][j],     q1 = ew[m][j + 1];
        const float q2 = ew[m][j + 2], q3 = ew[m][j + 3];
        acc += x[s0 * F0 + f] * q0 + x[s1 * F0 + f] * q1 +
               x[s2 * F0 + f] * q2 + x[s3 * F0 + f] * q3;
      }
      for (; j < deg; ++j) acc += x[es[m][j] * F0 + f] * ew[m][j];
      alds[m * F0 + f] = di * acc;
    }
  }
  __syncthreads();
  {  // phase A: thread = layer-1 channel c; writes h1h fp16 (k-contig per m)
    const int c = tid;
    float w1r[F0];
#pragma unroll
    for (int k = 0; k < F0; ++k) w1r[k] = W1[k * F1 + c];
    const float bb = b1[c];
#pragma unroll
    for (int m = 0; m < MB; ++m) {
      float acc = bb;
#pragma unroll
      for (int k = 0; k < F0; ++k) acc += alds[m * F0 + k] * w1r[k];
      h1h[m * H1S + c] = (_Float16)fmaxf(acc, 0.f);
    }
  }
  // phase B: MFMA. Wave wv owns 2 output tiles (16 nodes x 16 cols) at
  // n-offsets wv*32, wv*32+16. K=256 in 4 chunks of 64, reg-prefetch staging.
  const int lane = tid & 63;
  const int wv   = tid >> 6;
  const int lr   = lane & 15;
  const int lg   = lane >> 4;
  const int nt0  = wv * 32;
  f32x4 acc0 = {0.f, 0.f, 0.f, 0.f};
  f32x4 acc1 = {0.f, 0.f, 0.f, 0.f};
  // LDS store map for staged chunk: uint4 idx = (u>>3)*9 + (u&7)
  uint4* w2t4 = (uint4*)w2t;
  const int sb = (tid >> 3) * 9 + (tid & 7);
  for (int kc = 0; kc < F1 / BKC; ++kc) {
    __syncthreads();  // prev chunk consumed (kc=0: h1h written by phase A)
    w2t4[sb]       = pf0;
    w2t4[sb + 288] = pf1;
    w2t4[sb + 576] = pf2;
    w2t4[sb + 864] = pf3;
    __syncthreads();
    if (kc + 1 < F1 / BKC) {  // issue next-chunk loads
      const uint4* gnext = W2t4 + (kc + 1) * 8;
      pf0 = gnext[gb];
      pf1 = gnext[gb + 1024];
      pf2 = gnext[gb + 2048];
      pf3 = gnext[gb + 3072];
    }
#pragma unroll
    for (int ks = 0; ks < 2; ++ks) {
      const int kb = kc * BKC + ks * 32;         // global k base
      const f16x8 av = *(const f16x8*)&h1h[lr * H1S + kb + lg * 8];
      const f16x8 b0 = *(const f16x8*)&w2t[(nt0 + lr) * W2S + ks * 32 + lg * 8];
      const f16x8 b1v = *(const f16x8*)&w2t[(nt0 + 16 + lr) * W2S + ks * 32 + lg * 8];
      acc0 = __builtin_amdgcn_mfma_f32_16x16x32_f16(av, b0, acc0, 0, 0, 0);
      acc1 = __builtin_amdgcn_mfma_f32_16x16x32_f16(av, b1v, acc1, 0, 0, 0);
    }
  }
  // epilogue: C/D layout col=lane&15, row=(lane>>4)*4+reg; scale by din[row]
#pragma unroll
  for (int r = 0; r < 4; ++r) {
    const int row = lg * 4 + r;
    const float dn = din[row];
    t2h[(size_t)(n0 + row) * F2 + nt0 + lr]      = (_Float16)(acc0[r] * dn);
    t2h[(size_t)(n0 + row) * F2 + nt0 + 16 + lr] = (_Float16)(acc1[r] * dn);
  }
}

// ---------- layer-2 aggregation + layer-3 transform ----------
// 2 nodes per wave: half-wave (32 lanes) per node, 8 B/lane (4 fp16);
// 16 gathers in flight (deg~16).

__device__ inline void acc_h4(uint2 u, float& a0, float& a1, float& a2, float& a3) {
  union { uint2 u; __half2 h[2]; } pk;
  pk.u = u;
  const float2 f0 = __half22float2(pk.h[0]);
  const float2 f1 = __half22float2(pk.h[1]);
  a0 += f0.x; a1 += f0.y; a2 += f1.x; a3 += f1.y;
}

__global__ __launch_bounds__(256) void k_agg2(
    const __half* __restrict__ t2h, const int* __restrict__ cursor,
    const int* __restrict__ col, const float* __restrict__ b2,
    const float* __restrict__ W3, float* __restrict__ t3s) {
  const int wave = (blockIdx.x * 256 + threadIdx.x) >> 6;
  const int lane = threadIdx.x & 63;
  const int half = lane >> 5;        // 0 or 1
  const int li   = lane & 31;
  const int n    = wave * 2 + half;  // 2500 blocks cover 20000 exactly
  if (n >= NN) return;
  const int deg = cursor[n];
  const int base = n * CAP;
  const int fx = li * 4;
  float a0 = 0.f, a1 = 0.f, a2 = 0.f, a3 = 0.f;
  acc_h4(*(const uint2*)&t2h[(size_t)n * F2 + fx], a0, a1, a2, a3);  // self
  int k = 0;
  for (; k + 15 < deg; k += 16) {  // 16 coalesced 256B gathers in flight
    int ss[16];
#pragma unroll
    for (int j = 0; j < 16; ++j) ss[j] = col[base + k + j];
    uint2 vv[16];
#pragma unroll
    for (int j = 0; j < 16; ++j)
      vv[j] = *(const uint2*)&t2h[(size_t)ss[j] * F2 + fx];
#pragma unroll
    for (int j = 0; j < 16; ++j) acc_h4(vv[j], a0, a1, a2, a3);
  }
  for (; k + 7 < deg; k += 8) {
    int ss[8];
#pragma unroll
    for (int j = 0; j < 8; ++j) ss[j] = col[base + k + j];
    uint2 vv[8];
#pragma unroll
    for (int j = 0; j < 8; ++j)
      vv[j] = *(const uint2*)&t2h[(size_t)ss[j] * F2 + fx];
#pragma unroll
    for (int j = 0; j < 8; ++j) acc_h4(vv[j], a0, a1, a2, a3);
  }
  for (; k + 3 < deg; k += 4) {
    int ss[4];
#pragma unroll
    for (int j = 0; j < 4; ++j) ss[j] = col[base + k + j];
    uint2 vv[4];
#pragma unroll
    for (int j = 0; j < 4; ++j)
      vv[j] = *(const uint2*)&t2h[(size_t)ss[j] * F2 + fx];
#pragma unroll
    for (int j = 0; j < 4; ++j) acc_h4(vv[j], a0, a1, a2, a3);
  }
  for (; k < deg; ++k) {
    acc_h4(*(const uint2*)&t2h[(size_t)col[base + k] * F2 + fx], a0, a1, a2, a3);
  }
  const float di = rsqrtf((float)(deg + 1));
  const float4 bb = *(const float4*)&b2[fx];
  const float4 w3 = *(const float4*)&W3[fx];
  const float h0 = fmaxf(di * a0 + bb.x, 0.f);
  const float h1 = fmaxf(di * a1 + bb.y, 0.f);
  const float h2 = fmaxf(di * a2 + bb.z, 0.f);
  const float h3 = fmaxf(di * a3 + bb.w, 0.f);
  float p = (h0 * w3.x + h1 * w3.y) + (h2 * w3.z + h3 * w3.w);
#pragma unroll
  for (int off = 16; off > 0; off >>= 1) p += __shfl_down(p, off);  // within half
  if (li == 0) t3s[n] = di * p;
}

// ---------- layer-3 aggregation ----------
// 4 nodes per wave, 16 lanes per node -> coalesced col reads, 16-wide gathers.

__global__ __launch_bounds__(256) void k_agg3(
    const float* __restrict__ t3s, const int* __restrict__ cursor,
    const int* __restrict__ col, const float* __restrict__ b3,
    float* __restrict__ out) {
  const int wave = (blockIdx.x * 256 + threadIdx.x) >> 6;
  const int lane = threadIdx.x & 63;
  const int sub  = lane >> 4;       // 0..3
  const int li   = lane & 15;
  const int n    = wave * 4 + sub;  // 1250 blocks x 16 nodes cover 20000 exactly
  if (n >= NN) return;
  const int deg = cursor[n];
  const int base = n * CAP;
  float acc = 0.f;
  for (int j = li; j < deg; j += 16) acc += t3s[col[base + j]];
  acc += __shfl_xor(acc, 8);
  acc += __shfl_xor(acc, 4);
  acc += __shfl_xor(acc, 2);
  acc += __shfl_xor(acc, 1);
  if (li == 0)
    out[n] = rsqrtf((float)(deg + 1)) * (acc + t3s[n]) + b3[0];
}

extern "C" void kernel_launch(void* const* d_in, const int* in_sizes, int n_in,
                              void* d_out, int out_size, void* d_ws, size_t ws_size,
                              hipStream_t stream) {
  const float* x = (const float*)d_in[0];
  const int* ei = (const int*)d_in[1];
  const int* srcv = ei;       // edge_index[0]
  const int* dstv = ei + NE;  // edge_index[1]
  const float* W1 = (const float*)d_in[2];
  const float* b1 = (const float*)d_in[3];
  const float* W2 = (const float*)d_in[4];
  const float* b2 = (const float*)d_in[5];
  const float* W3 = (const float*)d_in[6];
  const float* b3 = (const float*)d_in[7];
  float* out = (float*)d_out;

  char* w = (char*)d_ws;
  auto alloc = [&](size_t bytes) -> void* {
    void* p = (void*)w;
    w += (bytes + 255) & ~(size_t)255;
    return p;
  };
  int*      cursor = (int*)     alloc(NN * 4);
  int*      col    = (int*)     alloc((size_t)NN * CAP * 4);
  _Float16* t2h    = (_Float16*)alloc((size_t)NN * F2 * 2);
  float*    t3s    = (float*)   alloc(NN * 4);
  _Float16* W2t    = (_Float16*)alloc((size_t)F2 * F1 * 2);

  k_prep<<<(F1 * F2) / 256, 256, 0, stream>>>(W2, W2t, cursor);
  k_fill<<<(NE / 2 + 255) / 256, 256, 0, stream>>>(srcv, dstv, cursor, col);
  k_gemm12<<<NN / MB, 256, 0, stream>>>(x, cursor, col, W1, b1, W2t, t2h);
  k_agg2<<<NN / 8, 256, 0, stream>>>((const __half*)t2h, cursor, col, b2, W3, t3s);
  k_agg3<<<(NN + 15) / 16, 256, 0, stream>>>(t3s, cursor, col, b3, out);
}

// Round 8
// 122.734 us; speedup vs baseline: 1.0383x; 1.0189x over previous
//
#include <hip/hip_runtime.h>
#include <hip/hip_fp16.h>

// 3-layer GCN on MI355X — R24: gemm12 LDS diet -> 5 blocks/CU.
// Plateau analysis (R20-R23, all ~124-125us): ~45us harness poison-fill
// (fixed, in-window) + ~80us controllable. Largest controllable term =
// gemm12 (~20-22us), LDS 33.8KB -> 4 blocks/CU, stage-0 latency-sensitive.
// R24: es staged as USHORT (ids<20000), ew array DELETED (stage-0b recomputes
// rsqrtf(cursor[s]+1); 10 lanes/node read the same cursor address = one
// coalesced L1-hot line; identical fp math in identical order -> absmax
// bit-identical). LDS 33.8 -> 28.5KB -> 5 blocks/CU (+25% waves).
// Structure: k_prep (W2 transpose fp16 + cursor zero) -> k_fill (int2) ->
//   k_gemm12 (agg1 + L1 + MFMA L2 -> t2h fp16) -> k_agg2 -> k_agg3.
// Fragment layouts (m89/m97-verified): A/B: row(m)|col(n) = lane&15,
// k = (lane>>4)*8 + i (b128 per lane); C/D: col = lane&15,
// row = (lane>>4)*4 + reg.
// Lessons (all measured): R3 multi-float atomic scatter=186us; R4 cooperative
// grid.sync~100us each; R7/R13/R22 W2 from global in phase B = latency-bound
// at ANY intensity — W2 must be LDS-staged (chunked, reg-prefetch);
// R9/R11/R16 MB=32 loses 2-6us; R14 128t blocks can't hide chunk barriers;
// R17 8-node k-split phase B = VGPR 128, occ 17%, -11us; R18 coop stage-0 =
// +0.8us; R19 fp16 t2s + 16-lane agg3 = -9.9us, absmax 1.2e-4 OK; R20 MFMA
// fp16 phase B = -13.3us; R21 16-deep agg2 + prep fusion = neutral (agg2 at
// random-gather floor); R22 global-B phase B = +2-3us REGRESSION;
// R23 int2 fill = neutral.

constexpr int NN  = 20000;  // nodes
constexpr int NE  = 320000; // edges
constexpr int F0  = 10;     // input feats
constexpr int F1  = 256;    // layer1 out
constexpr int F2  = 128;    // layer2 out
constexpr int MB  = 16;     // nodes per gemm12 tile (= MFMA M)
constexpr int CAP = 64;     // bucket capacity (max in-deg ~36)
constexpr int EMAX = 48;    // staged edges per node

typedef _Float16 f16x8 __attribute__((ext_vector_type(8)));
typedef float    f32x4 __attribute__((ext_vector_type(4)));

constexpr int H1S = 264;    // h1h row stride (f16): mult of 8, 528B rows
constexpr int BKC = 64;     // K per staged chunk
constexpr int W2S = 72;     // w2t_lds row stride (f16): mult of 8, 144B rows

// ---------- adjacency fill: 2 edges/thread via int2 ----------

__global__ void k_fill(const int* __restrict__ src, const int* __restrict__ dst,
                       int* cursor, int* __restrict__ col) {
  const int t = blockIdx.x * 256 + threadIdx.x;  // 160000 threads
  if (t * 2 >= NE) return;
  const int2 s2 = *(const int2*)&src[t * 2];
  const int2 d2 = *(const int2*)&dst[t * 2];
  const int p0 = atomicAdd(&cursor[d2.x], 1) & (CAP - 1);
  col[d2.x * CAP + p0] = s2.x;
  const int p1 = atomicAdd(&cursor[d2.y], 1) & (CAP - 1);
  col[d2.y * CAP + p1] = s2.y;
}

// ---------- prep: W2 transpose to fp16 [n][k] + cursor zeroing ----------

__global__ __launch_bounds__(256) void k_prep(const float* __restrict__ W2,
                                              _Float16* __restrict__ W2t,
                                              int* __restrict__ cursor) {
  const int t = blockIdx.x * 256 + threadIdx.x;  // 32768 total
  const int n = t >> 8;        // 0..127
  const int k = t & 255;       // 0..255
  W2t[n * 256 + k] = (_Float16)W2[k * F2 + n];
  if (t < NN) cursor[t] = 0;
}

// ---------- fused: agg1 -> h1 = relu(.) fp16 -> t2h = fp16(dinv*(h1 W2)) ----

__global__ __launch_bounds__(256) void k_gemm12(
    const float* __restrict__ x, const int* __restrict__ cursor,
    const int* __restrict__ col, const float* __restrict__ W1,
    const float* __restrict__ b1, const _Float16* __restrict__ W2t,
    _Float16* __restrict__ t2h) {
  __shared__ float alds[MB * F0];                       // 640 B
  __shared__ float din[MB];                             // 64 B
  __shared__ __align__(16) _Float16 h1h[MB * H1S];      // 8.25 KB
  __shared__ __align__(16) _Float16 w2t[F2 * W2S];      // 18 KB
  __shared__ unsigned short es[MB][EMAX];               // 1.5 KB
  const int tid = threadIdx.x;
  const int n0 = blockIdx.x * MB;
  // W2t chunk-0 prefetch FIRST: in flight under all of stage 0.
  // uint4 index map: u in {tid, tid+256, tid+512, tid+768}:
  //   n = u>>3, koff16B = u&7 ; global uint4 idx = n*32 + kc*8 + (u&7)
  const uint4* W2t4 = (const uint4*)W2t;
  const int gb = ((tid >> 3) << 5) + (tid & 7);
  uint4 pf0 = W2t4[gb];
  uint4 pf1 = W2t4[gb + 1024];
  uint4 pf2 = W2t4[gb + 2048];
  uint4 pf3 = W2t4[gb + 3072];
  // stage 0a: cooperative edge staging — 16 threads per node, one edge each.
  {
    const int m = tid >> 4;
    const int j0 = tid & 15;
    const int n = n0 + m;
    const int degraw = cursor[n];
    const int deg = min(degraw, EMAX);
    const int base = n * CAP;
    if (j0 == 0) din[m] = rsqrtf((float)(degraw + 1));
    for (int j = j0; j < deg; j += 16)
      es[m][j] = (unsigned short)col[base + j];
  }
  __syncthreads();
  // stage 0b: x-gathers with LDS-sourced addresses; edge weight recomputed
  // per f-lane (10 lanes read the SAME cursor[s] line — coalesced, L1-hot;
  // identical fp math/order as staged version -> bit-identical result).
  {
    const int m = tid >> 4;
    const int f = tid & 15;
    if (f < F0) {
      const int n = n0 + m;
      const int deg = min(cursor[n], EMAX);
      const float di = din[m];
      float acc = x[n * F0 + f] * di;  // self-loop
      int j = 0;
      for (; j + 3 < deg; j += 4) {
        const int s0 = es[m][j],     s1 = es[m][j + 1];
        const int s2 = es[m][j + 2], s3 = es[m][j + 3];
        const float q0 = rsqrtf((float)(cursor[s0] + 1));
        const float q1 = rsqrtf((float)(cursor[s1] + 1));
        const float q2 = rsqrtf((float)(cursor[s2] + 1));
        const float q3 = rsqrtf((float)(cursor[s3] + 1));
        acc += x[s0 * F0 + f] * q0 + x[s1 * F0 + f] * q1 +
               x[s2 * F0 + f] * q2 + x[s3 * F0 + f] * q3;
      }
      for (; j < deg; ++j) {
        const int s = es[m][j];
        acc += x[s * F0 + f] * rsqrtf((float)(cursor[s] + 1));
      }
      alds[m * F0 + f] = di * acc;
    }
  }
  __syncthreads();
  {  // phase A: thread = layer-1 channel c; writes h1h fp16 (k-contig per m)
    const int c = tid;
    float w1r[F0];
#pragma unroll
    for (int k = 0; k < F0; ++k) w1r[k] = W1[k * F1 + c];
    const float bb = b1[c];
#pragma unroll
    for (int m = 0; m < MB; ++m) {
      float acc = bb;
#pragma unroll
      for (int k = 0; k < F0; ++k) acc += alds[m * F0 + k] * w1r[k];
      h1h[m * H1S + c] = (_Float16)fmaxf(acc, 0.f);
    }
  }
  // phase B: MFMA. Wave wv owns 2 output tiles (16 nodes x 16 cols) at
  // n-offsets wv*32, wv*32+16. K=256 in 4 chunks of 64, reg-prefetch staging.
  const int lane = tid & 63;
  const int wv   = tid >> 6;
  const int lr   = lane & 15;
  const int lg   = lane >> 4;
  const int nt0  = wv * 32;
  f32x4 acc0 = {0.f, 0.f, 0.f, 0.f};
  f32x4 acc1 = {0.f, 0.f, 0.f, 0.f};
  // LDS store map for staged chunk: uint4 idx = (u>>3)*9 + (u&7)
  uint4* w2t4 = (uint4*)w2t;
  const int sb = (tid >> 3) * 9 + (tid & 7);
  for (int kc = 0; kc < F1 / BKC; ++kc) {
    __syncthreads();  // prev chunk consumed (kc=0: h1h written by phase A)
    w2t4[sb]       = pf0;
    w2t4[sb + 288] = pf1;
    w2t4[sb + 576] = pf2;
    w2t4[sb + 864] = pf3;
    __syncthreads();
    if (kc + 1 < F1 / BKC) {  // issue next-chunk loads
      const uint4* gnext = W2t4 + (kc + 1) * 8;
      pf0 = gnext[gb];
      pf1 = gnext[gb + 1024];
      pf2 = gnext[gb + 2048];
      pf3 = gnext[gb + 3072];
    }
#pragma unroll
    for (int ks = 0; ks < 2; ++ks) {
      const int kb = kc * BKC + ks * 32;         // global k base
      const f16x8 av = *(const f16x8*)&h1h[lr * H1S + kb + lg * 8];
      const f16x8 b0 = *(const f16x8*)&w2t[(nt0 + lr) * W2S + ks * 32 + lg * 8];
      const f16x8 b1v = *(const f16x8*)&w2t[(nt0 + 16 + lr) * W2S + ks * 32 + lg * 8];
      acc0 = __builtin_amdgcn_mfma_f32_16x16x32_f16(av, b0, acc0, 0, 0, 0);
      acc1 = __builtin_amdgcn_mfma_f32_16x16x32_f16(av, b1v, acc1, 0, 0, 0);
    }
  }
  // epilogue: C/D layout col=lane&15, row=(lane>>4)*4+reg; scale by din[row]
#pragma unroll
  for (int r = 0; r < 4; ++r) {
    const int row = lg * 4 + r;
    const float dn = din[row];
    t2h[(size_t)(n0 + row) * F2 + nt0 + lr]      = (_Float16)(acc0[r] * dn);
    t2h[(size_t)(n0 + row) * F2 + nt0 + 16 + lr] = (_Float16)(acc1[r] * dn);
  }
}

// ---------- layer-2 aggregation + layer-3 transform ----------
// 2 nodes per wave: half-wave (32 lanes) per node, 8 B/lane (4 fp16);
// 16 gathers in flight (deg~16).

__device__ inline void acc_h4(uint2 u, float& a0, float& a1, float& a2, float& a3) {
  union { uint2 u; __half2 h[2]; } pk;
  pk.u = u;
  const float2 f0 = __half22float2(pk.h[0]);
  const float2 f1 = __half22float2(pk.h[1]);
  a0 += f0.x; a1 += f0.y; a2 += f1.x; a3 += f1.y;
}

__global__ __launch_bounds__(256) void k_agg2(
    const __half* __restrict__ t2h, const int* __restrict__ cursor,
    const int* __restrict__ col, const float* __restrict__ b2,
    const float* __restrict__ W3, float* __restrict__ t3s) {
  const int wave = (blockIdx.x * 256 + threadIdx.x) >> 6;
  const int lane = threadIdx.x & 63;
  const int half = lane >> 5;        // 0 or 1
  const int li   = lane & 31;
  const int n    = wave * 2 + half;  // 2500 blocks cover 20000 exactly
  if (n >= NN) return;
  const int deg = cursor[n];
  const int base = n * CAP;
  const int fx = li * 4;
  float a0 = 0.f, a1 = 0.f, a2 = 0.f, a3 = 0.f;
  acc_h4(*(const uint2*)&t2h[(size_t)n * F2 + fx], a0, a1, a2, a3);  // self
  int k = 0;
  for (; k + 15 < deg; k += 16) {  // 16 coalesced 256B gathers in flight
    int ss[16];
#pragma unroll
    for (int j = 0; j < 16; ++j) ss[j] = col[base + k + j];
    uint2 vv[16];
#pragma unroll
    for (int j = 0; j < 16; ++j)
      vv[j] = *(const uint2*)&t2h[(size_t)ss[j] * F2 + fx];
#pragma unroll
    for (int j = 0; j < 16; ++j) acc_h4(vv[j], a0, a1, a2, a3);
  }
  for (; k + 7 < deg; k += 8) {
    int ss[8];
#pragma unroll
    for (int j = 0; j < 8; ++j) ss[j] = col[base + k + j];
    uint2 vv[8];
#pragma unroll
    for (int j = 0; j < 8; ++j)
      vv[j] = *(const uint2*)&t2h[(size_t)ss[j] * F2 + fx];
#pragma unroll
    for (int j = 0; j < 8; ++j) acc_h4(vv[j], a0, a1, a2, a3);
  }
  for (; k + 3 < deg; k += 4) {
    int ss[4];
#pragma unroll
    for (int j = 0; j < 4; ++j) ss[j] = col[base + k + j];
    uint2 vv[4];
#pragma unroll
    for (int j = 0; j < 4; ++j)
      vv[j] = *(const uint2*)&t2h[(size_t)ss[j] * F2 + fx];
#pragma unroll
    for (int j = 0; j < 4; ++j) acc_h4(vv[j], a0, a1, a2, a3);
  }
  for (; k < deg; ++k) {
    acc_h4(*(const uint2*)&t2h[(size_t)col[base + k] * F2 + fx], a0, a1, a2, a3);
  }
  const float di = rsqrtf((float)(deg + 1));
  const float4 bb = *(const float4*)&b2[fx];
  const float4 w3 = *(const float4*)&W3[fx];
  const float h0 = fmaxf(di * a0 + bb.x, 0.f);
  const float h1 = fmaxf(di * a1 + bb.y, 0.f);
  const float h2 = fmaxf(di * a2 + bb.z, 0.f);
  const float h3 = fmaxf(di * a3 + bb.w, 0.f);
  float p = (h0 * w3.x + h1 * w3.y) + (h2 * w3.z + h3 * w3.w);
#pragma unroll
  for (int off = 16; off > 0; off >>= 1) p += __shfl_down(p, off);  // within half
  if (li == 0) t3s[n] = di * p;
}

// ---------- layer-3 aggregation ----------
// 4 nodes per wave, 16 lanes per node -> coalesced col reads, 16-wide gathers.

__global__ __launch_bounds__(256) void k_agg3(
    const float* __restrict__ t3s, const int* __restrict__ cursor,
    const int* __restrict__ col, const float* __restrict__ b3,
    float* __restrict__ out) {
  const int wave = (blockIdx.x * 256 + threadIdx.x) >> 6;
  const int lane = threadIdx.x & 63;
  const int sub  = lane >> 4;       // 0..3
  const int li   = lane & 15;
  const int n    = wave * 4 + sub;  // 1250 blocks x 16 nodes cover 20000 exactly
  if (n >= NN) return;
  const int deg = cursor[n];
  const int base = n * CAP;
  float acc = 0.f;
  for (int j = li; j < deg; j += 16) acc += t3s[col[base + j]];
  acc += __shfl_xor(acc, 8);
  acc += __shfl_xor(acc, 4);
  acc += __shfl_xor(acc, 2);
  acc += __shfl_xor(acc, 1);
  if (li == 0)
    out[n] = rsqrtf((float)(deg + 1)) * (acc + t3s[n]) + b3[0];
}

extern "C" void kernel_launch(void* const* d_in, const int* in_sizes, int n_in,
                              void* d_out, int out_size, void* d_ws, size_t ws_size,
                              hipStream_t stream) {
  const float* x = (const float*)d_in[0];
  const int* ei = (const int*)d_in[1];
  const int* srcv = ei;       // edge_index[0]
  const int* dstv = ei + NE;  // edge_index[1]
  const float* W1 = (const float*)d_in[2];
  const float* b1 = (const float*)d_in[3];
  const float* W2 = (const float*)d_in[4];
  const float* b2 = (const float*)d_in[5];
  const float* W3 = (const float*)d_in[6];
  const float* b3 = (const float*)d_in[7];
  float* out = (float*)d_out;

  char* w = (char*)d_ws;
  auto alloc = [&](size_t bytes) -> void* {
    void* p = (void*)w;
    w += (bytes + 255) & ~(size_t)255;
    return p;
  };
  int*      cursor = (int*)     alloc(NN * 4);
  int*      col    = (int*)     alloc((size_t)NN * CAP * 4);
  _Float16* t2h    = (_Float16*)alloc((size_t)NN * F2 * 2);
  float*    t3s    = (float*)   alloc(NN * 4);
  _Float16* W2t    = (_Float16*)alloc((size_t)F2 * F1 * 2);

  k_prep<<<(F1 * F2) / 256, 256, 0, stream>>>(W2, W2t, cursor);
  k_fill<<<(NE / 2 + 255) / 256, 256, 0, stream>>>(srcv, dstv, cursor, col);
  k_gemm12<<<NN / MB, 256, 0, stream>>>(x, cursor, col, W1, b1, W2t, t2h);
  k_agg2<<<NN / 8, 256, 0, stream>>>((const __half*)t2h, cursor, col, b2, W3, t3s);
  k_agg3<<<(NN + 15) / 16, 256, 0, stream>>>(t3s, cursor, col, b3, out);
}

// Round 9
// 120.873 us; speedup vs baseline: 1.0543x; 1.0154x over previous
//
#include <hip/hip_runtime.h>
#include <hip/hip_fp16.h>

// 3-layer GCN on MI355X — R25: fragment-ordered W2t -> barrier-free phase B.
// Insight: phase B's LDS W2 staging has ZERO inter-wave sharing (each staged
// row consumed by exactly one wave) — it existed only as a prefetch pipe.
// R22's direct-global failure was a COALESCING failure (fragment loads at
// lane-stride 512B = 16 lines/instr), not a latency law. Fix at the source:
// k_prep writes W2t in MFMA-FRAGMENT ORDER (idx = (tile*8+ks)*64+lane, f16x8
// granules) -> a wave's B-load is lane-consecutive 16B = 4 lines/instr,
// L2/L3-hot (64KB shared by 1250 blocks). Phase B: no W2 LDS, no chunk loop,
// no prefetch regs, ONE barrier after phase A; 8 unrolled k-steps of
// {1 LDS A-read, 2 coalesced B-reads, 2 MFMA}. LDS 28.5 -> 10.7 KB.
// Identical fragment values/order -> absmax bit-identical (1.2e-4).
// Structure: k_prep (W2 fragment-transpose fp16 + cursor zero) -> k_fill
//   (int2) -> k_gemm12 -> k_agg2 -> k_agg3.
// Fragment layouts (m89/m97-verified): A/B: row(m)|col(n) = lane&15,
// k = (lane>>4)*8 + i (b128 per lane); C/D: col = lane&15,
// row = (lane>>4)*4 + reg.
// Lessons (all measured): R3 multi-float atomic scatter=186us; R4 cooperative
// grid.sync~100us each; R22 fragment-layout global B-loads UNCOALESCED
// (16 lines/instr) = +2-3us — coalescing, not staging, was the requirement;
// R9/R11/R16 MB=32 loses 2-6us; R14 128t blocks can't hide chunk barriers;
// R17 8-node k-split phase B = VGPR 128, occ 17%, -11us; R18 coop stage-0 =
// +0.8us; R19 fp16 t2s + 16-lane agg3 = -9.9us, absmax 1.2e-4 OK; R20 MFMA
// fp16 phase B = -13.3us; R21 16-deep agg2 + prep fusion = neutral (agg2 at
// random-gather floor); R23 int2 fill = neutral; R24 LDS diet (ushort es,
// ew recompute) = -2.3us.

constexpr int NN  = 20000;  // nodes
constexpr int NE  = 320000; // edges
constexpr int F0  = 10;     // input feats
constexpr int F1  = 256;    // layer1 out
constexpr int F2  = 128;    // layer2 out
constexpr int MB  = 16;     // nodes per gemm12 tile (= MFMA M)
constexpr int CAP = 64;     // bucket capacity (max in-deg ~36)
constexpr int EMAX = 48;    // staged edges per node

typedef _Float16 f16x8 __attribute__((ext_vector_type(8)));
typedef float    f32x4 __attribute__((ext_vector_type(4)));

constexpr int H1S = 264;    // h1h row stride (f16): mult of 8, 528B rows

// ---------- adjacency fill: 2 edges/thread via int2 ----------

__global__ void k_fill(const int* __restrict__ src, const int* __restrict__ dst,
                       int* cursor, int* __restrict__ col) {
  const int t = blockIdx.x * 256 + threadIdx.x;  // 160000 threads
  if (t * 2 >= NE) return;
  const int2 s2 = *(const int2*)&src[t * 2];
  const int2 d2 = *(const int2*)&dst[t * 2];
  const int p0 = atomicAdd(&cursor[d2.x], 1) & (CAP - 1);
  col[d2.x * CAP + p0] = s2.x;
  const int p1 = atomicAdd(&cursor[d2.y], 1) & (CAP - 1);
  col[d2.y * CAP + p1] = s2.y;
}

// ---------- prep: W2 -> fp16 fragment-ordered W2t + cursor zeroing ----------
// W2t element t: i = t&7, lane = (t>>3)&63, ks = (t>>9)&7, tile = t>>12;
// holds W2[k][n] with n = tile*16 + (lane&15), k = ks*32 + (lane>>4)*8 + i.
// A wave reading fragment (tile, ks) loads lane-consecutive f16x8 -> 4 lines.

__global__ __launch_bounds__(256) void k_prep(const float* __restrict__ W2,
                                              _Float16* __restrict__ W2t,
                                              int* __restrict__ cursor) {
  const int t = blockIdx.x * 256 + threadIdx.x;  // 32768 total
  const int i    = t & 7;
  const int lane = (t >> 3) & 63;
  const int ks   = (t >> 9) & 7;
  const int tile = t >> 12;        // 0..7
  const int n = tile * 16 + (lane & 15);
  const int k = ks * 32 + (lane >> 4) * 8 + i;
  W2t[t] = (_Float16)W2[k * F2 + n];
  if (t < NN) cursor[t] = 0;
}

// ---------- fused: agg1 -> h1 = relu(.) fp16 -> t2h = fp16(dinv*(h1 W2)) ----

__global__ __launch_bounds__(256) void k_gemm12(
    const float* __restrict__ x, const int* __restrict__ cursor,
    const int* __restrict__ col, const float* __restrict__ W1,
    const float* __restrict__ b1, const _Float16* __restrict__ W2t,
    _Float16* __restrict__ t2h) {
  __shared__ float alds[MB * F0];                       // 640 B
  __shared__ float din[MB];                             // 64 B
  __shared__ __align__(16) _Float16 h1h[MB * H1S];      // 8.25 KB
  __shared__ unsigned short es[MB][EMAX];               // 1.5 KB
  const int tid = threadIdx.x;
  const int n0 = blockIdx.x * MB;
  // stage 0a: cooperative edge staging — 16 threads per node, one edge each.
  {
    const int m = tid >> 4;
    const int j0 = tid & 15;
    const int n = n0 + m;
    const int degraw = cursor[n];
    const int deg = min(degraw, EMAX);
    const int base = n * CAP;
    if (j0 == 0) din[m] = rsqrtf((float)(degraw + 1));
    for (int j = j0; j < deg; j += 16)
      es[m][j] = (unsigned short)col[base + j];
  }
  __syncthreads();
  // stage 0b: x-gathers with LDS-sourced addresses; edge weight recomputed
  // per f-lane (10 lanes read the SAME cursor[s] line — coalesced, L1-hot;
  // identical fp math/order -> bit-identical result).
  {
    const int m = tid >> 4;
    const int f = tid & 15;
    if (f < F0) {
      const int n = n0 + m;
      const int deg = min(cursor[n], EMAX);
      const float di = din[m];
      float acc = x[n * F0 + f] * di;  // self-loop
      int j = 0;
      for (; j + 3 < deg; j += 4) {
        const int s0 = es[m][j],     s1 = es[m][j + 1];
        const int s2 = es[m][j + 2], s3 = es[m][j + 3];
        const float q0 = rsqrtf((float)(cursor[s0] + 1));
        const float q1 = rsqrtf((float)(cursor[s1] + 1));
        const float q2 = rsqrtf((float)(cursor[s2] + 1));
        const float q3 = rsqrtf((float)(cursor[s3] + 1));
        acc += x[s0 * F0 + f] * q0 + x[s1 * F0 + f] * q1 +
               x[s2 * F0 + f] * q2 + x[s3 * F0 + f] * q3;
      }
      for (; j < deg; ++j) {
        const int s = es[m][j];
        acc += x[s * F0 + f] * rsqrtf((float)(cursor[s] + 1));
      }
      alds[m * F0 + f] = di * acc;
    }
  }
  __syncthreads();
  {  // phase A: thread = layer-1 channel c; writes h1h fp16 (k-contig per m)
    const int c = tid;
    float w1r[F0];
#pragma unroll
    for (int k = 0; k < F0; ++k) w1r[k] = W1[k * F1 + c];
    const float bb = b1[c];
#pragma unroll
    for (int m = 0; m < MB; ++m) {
      float acc = bb;
#pragma unroll
      for (int k = 0; k < F0; ++k) acc += alds[m * F0 + k] * w1r[k];
      h1h[m * H1S + c] = (_Float16)fmaxf(acc, 0.f);
    }
  }
  __syncthreads();  // h1h visible to all waves; LAST barrier in the kernel
  // phase B: barrier-free MFMA. Wave wv owns 2 tiles (16 nodes x 16 cols) at
  // n-offsets wv*32, wv*32+16. B-fragments from fragment-ordered W2t:
  // lane-consecutive f16x8 -> coalesced 4-line loads, 64KB L2/L3-hot.
  const int lane = tid & 63;
  const int wv   = tid >> 6;
  const int lr   = lane & 15;
  const int lg   = lane >> 4;
  const int nt0  = wv * 32;
  f32x4 acc0 = {0.f, 0.f, 0.f, 0.f};
  f32x4 acc1 = {0.f, 0.f, 0.f, 0.f};
  const f16x8* bfrag = (const f16x8*)W2t;  // idx = (tile*8 + ks)*64 + lane
  const int t0 = wv * 2, t1 = t0 + 1;
#pragma unroll
  for (int ks = 0; ks < 8; ++ks) {  // K=256 in 8 steps of 32
    const f16x8 av  = *(const f16x8*)&h1h[lr * H1S + ks * 32 + lg * 8];
    const f16x8 b0  = bfrag[(t0 * 8 + ks) * 64 + lane];
    const f16x8 b1v = bfrag[(t1 * 8 + ks) * 64 + lane];
    acc0 = __builtin_amdgcn_mfma_f32_16x16x32_f16(av, b0, acc0, 0, 0, 0);
    acc1 = __builtin_amdgcn_mfma_f32_16x16x32_f16(av, b1v, acc1, 0, 0, 0);
  }
  // epilogue: C/D layout col=lane&15, row=(lane>>4)*4+reg; scale by din[row]
#pragma unroll
  for (int r = 0; r < 4; ++r) {
    const int row = lg * 4 + r;
    const float dn = din[row];
    t2h[(size_t)(n0 + row) * F2 + nt0 + lr]      = (_Float16)(acc0[r] * dn);
    t2h[(size_t)(n0 + row) * F2 + nt0 + 16 + lr] = (_Float16)(acc1[r] * dn);
  }
}

// ---------- layer-2 aggregation + layer-3 transform ----------
// 2 nodes per wave: half-wave (32 lanes) per node, 8 B/lane (4 fp16);
// 16 gathers in flight (deg~16).

__device__ inline void acc_h4(uint2 u, float& a0, float& a1, float& a2, float& a3) {
  union { uint2 u; __half2 h[2]; } pk;
  pk.u = u;
  const float2 f0 = __half22float2(pk.h[0]);
  const float2 f1 = __half22float2(pk.h[1]);
  a0 += f0.x; a1 += f0.y; a2 += f1.x; a3 += f1.y;
}

__global__ __launch_bounds__(256) void k_agg2(
    const __half* __restrict__ t2h, const int* __restrict__ cursor,
    const int* __restrict__ col, const float* __restrict__ b2,
    const float* __restrict__ W3, float* __restrict__ t3s) {
  const int wave = (blockIdx.x * 256 + threadIdx.x) >> 6;
  const int lane = threadIdx.x & 63;
  const int half = lane >> 5;        // 0 or 1
  const int li   = lane & 31;
  const int n    = wave * 2 + half;  // 2500 blocks cover 20000 exactly
  if (n >= NN) return;
  const int deg = cursor[n];
  const int base = n * CAP;
  const int fx = li * 4;
  float a0 = 0.f, a1 = 0.f, a2 = 0.f, a3 = 0.f;
  acc_h4(*(const uint2*)&t2h[(size_t)n * F2 + fx], a0, a1, a2, a3);  // self
  int k = 0;
  for (; k + 15 < deg; k += 16) {  // 16 coalesced 256B gathers in flight
    int ss[16];
#pragma unroll
    for (int j = 0; j < 16; ++j) ss[j] = col[base + k + j];
    uint2 vv[16];
#pragma unroll
    for (int j = 0; j < 16; ++j)
      vv[j] = *(const uint2*)&t2h[(size_t)ss[j] * F2 + fx];
#pragma unroll
    for (int j = 0; j < 16; ++j) acc_h4(vv[j], a0, a1, a2, a3);
  }
  for (; k + 7 < deg; k += 8) {
    int ss[8];
#pragma unroll
    for (int j = 0; j < 8; ++j) ss[j] = col[base + k + j];
    uint2 vv[8];
#pragma unroll
    for (int j = 0; j < 8; ++j)
      vv[j] = *(const uint2*)&t2h[(size_t)ss[j] * F2 + fx];
#pragma unroll
    for (int j = 0; j < 8; ++j) acc_h4(vv[j], a0, a1, a2, a3);
  }
  for (; k + 3 < deg; k += 4) {
    int ss[4];
#pragma unroll
    for (int j = 0; j < 4; ++j) ss[j] = col[base + k + j];
    uint2 vv[4];
#pragma unroll
    for (int j = 0; j < 4; ++j)
      vv[j] = *(const uint2*)&t2h[(size_t)ss[j] * F2 + fx];
#pragma unroll
    for (int j = 0; j < 4; ++j) acc_h4(vv[j], a0, a1, a2, a3);
  }
  for (; k < deg; ++k) {
    acc_h4(*(const uint2*)&t2h[(size_t)col[base + k] * F2 + fx], a0, a1, a2, a3);
  }
  const float di = rsqrtf((float)(deg + 1));
  const float4 bb = *(const float4*)&b2[fx];
  const float4 w3 = *(const float4*)&W3[fx];
  const float h0 = fmaxf(di * a0 + bb.x, 0.f);
  const float h1 = fmaxf(di * a1 + bb.y, 0.f);
  const float h2 = fmaxf(di * a2 + bb.z, 0.f);
  const float h3 = fmaxf(di * a3 + bb.w, 0.f);
  float p = (h0 * w3.x + h1 * w3.y) + (h2 * w3.z + h3 * w3.w);
#pragma unroll
  for (int off = 16; off > 0; off >>= 1) p += __shfl_down(p, off);  // within half
  if (li == 0) t3s[n] = di * p;
}

// ---------- layer-3 aggregation ----------
// 4 nodes per wave, 16 lanes per node -> coalesced col reads, 16-wide gathers.

__global__ __launch_bounds__(256) void k_agg3(
    const float* __restrict__ t3s, const int* __restrict__ cursor,
    const int* __restrict__ col, const float* __restrict__ b3,
    float* __restrict__ out) {
  const int wave = (blockIdx.x * 256 + threadIdx.x) >> 6;
  const int lane = threadIdx.x & 63;
  const int sub  = lane >> 4;       // 0..3
  const int li   = lane & 15;
  const int n    = wave * 4 + sub;  // 1250 blocks x 16 nodes cover 20000 exactly
  if (n >= NN) return;
  const int deg = cursor[n];
  const int base = n * CAP;
  float acc = 0.f;
  for (int j = li; j < deg; j += 16) acc += t3s[col[base + j]];
  acc += __shfl_xor(acc, 8);
  acc += __shfl_xor(acc, 4);
  acc += __shfl_xor(acc, 2);
  acc += __shfl_xor(acc, 1);
  if (li == 0)
    out[n] = rsqrtf((float)(deg + 1)) * (acc + t3s[n]) + b3[0];
}

extern "C" void kernel_launch(void* const* d_in, const int* in_sizes, int n_in,
                              void* d_out, int out_size, void* d_ws, size_t ws_size,
                              hipStream_t stream) {
  const float* x = (const float*)d_in[0];
  const int* ei = (const int*)d_in[1];
  const int* srcv = ei;       // edge_index[0]
  const int* dstv = ei + NE;  // edge_index[1]
  const float* W1 = (const float*)d_in[2];
  const float* b1 = (const float*)d_in[3];
  const float* W2 = (const float*)d_in[4];
  const float* b2 = (const float*)d_in[5];
  const float* W3 = (const float*)d_in[6];
  const float* b3 = (const float*)d_in[7];
  float* out = (float*)d_out;

  char* w = (char*)d_ws;
  auto alloc = [&](size_t bytes) -> void* {
    void* p = (void*)w;
    w += (bytes + 255) & ~(size_t)255;
    return p;
  };
  int*      cursor = (int*)     alloc(NN * 4);
  int*      col    = (int*)     alloc((size_t)NN * CAP * 4);
  _Float16* t2h    = (_Float16*)alloc((size_t)NN * F2 * 2);
  float*    t3s    = (float*)   alloc(NN * 4);
  _Float16* W2t    = (_Float16*)alloc((size_t)F2 * F1 * 2);

  k_prep<<<(F1 * F2) / 256, 256, 0, stream>>>(W2, W2t, cursor);
  k_fill<<<(NE / 2 + 255) / 256, 256, 0, stream>>>(srcv, dstv, cursor, col);
  k_gemm12<<<NN / MB, 256, 0, stream>>>(x, cursor, col, W1, b1, W2t, t2h);
  k_agg2<<<NN / 8, 256, 0, stream>>>((const __half*)t2h, cursor, col, b2, W3, t3s);
  k_agg3<<<(NN + 15) / 16, 256, 0, stream>>>(t3s, cursor, col, b3, out);
}